// Round 2
// baseline (92.434 us; speedup 1.0000x reference)
//
#include <hip/hip_runtime.h>

// Problem constants
#define N_PIX 4096   // 64*64 pixels
#define N_D   256    // feature dims
#define N_C   19     // classes
#define N_B   51     // bins

// ws layout (bytes) — every slot written unconditionally each launch (ws is poisoned)
#define OFF_PART   0       // float[18*64] per-block partial losses = 4608 B
#define OFF_COUNTS 4608    // int[19] (counts[1..18] written; [0] never read)

// --- K1 (fully fused): per-block bucket + stats + KDE + smooth-L1 + copy ---
// grid = (18, 64), block 256 = 4 waves; wave = one (c,d) row, lane = bin.
// Each block redundantly compacts class c's pixel list into LDS (labels are
// 16 KB, L2/L3-resident; 1152-way parallel beats a serial 19-block kernel).
// Norm factors 1/sqrt(2*pi*v) are row-constant -> cancel after normalization.
__global__ __launch_bounds__(256) void k_fused(const float* __restrict__ feature,
                                               const int* __restrict__ label,
                                               float* __restrict__ out,
                                               float* __restrict__ part,
                                               int* __restrict__ counts) {
    const int c = blockIdx.x + 1;                 // class 0 never reaches the loss
    const int w = threadIdx.x >> 6;
    const int lane = threadIdx.x & 63;
    const int d = (blockIdx.y << 2) | w;
    const int bid = blockIdx.x * 64 + blockIdx.y; // 0..1151

    __shared__ int lst[N_PIX];                    // class-c pixel indices (<=16 KB)
    __shared__ int wcnt[4];
    __shared__ float blk[4];

    // -- feature pass-through: striped over all 1152 blocks (4 KB/block),
    //    issued first so the loads/stores overlap everything below.
    //    NT stores: out is never re-read -> don't evict feature from L2. --
    {
        const int t = bid * 256 + threadIdx.x;    // 294912 threads total
        for (int i = t; i < N_PIX * N_D; i += 18 * 64 * 256)
            __builtin_nontemporal_store(feature[i], &out[1 + i]);
    }

    // -- bucket: each wave loads its 1024 labels ONCE into regs, counts,
    //    prefix-sums across waves, then scatters indices into LDS in order --
    int lab[16];
    const int q0 = w << 10;
#pragma unroll
    for (int i = 0; i < 16; ++i) lab[i] = label[q0 + (i << 6) + lane];

    int cnt = 0;
#pragma unroll
    for (int i = 0; i < 16; ++i) cnt += (int)__popcll(__ballot(lab[i] == c));
    if (lane == 0) wcnt[w] = cnt;
    __syncthreads();

    int off = 0, M = 0;
#pragma unroll
    for (int i = 0; i < 4; ++i) { const int v = wcnt[i]; off += (i < w) ? v : 0; M += v; }

#pragma unroll
    for (int i = 0; i < 16; ++i) {
        const bool match = (lab[i] == c);
        const unsigned long long mk = __ballot(match);
        if (match) lst[off + (int)__popcll(mk & ((1ull << lane) - 1ull))] = q0 + (i << 6) + lane;
        off += (int)__popcll(mk);
    }
    if (threadIdx.x == 0 && blockIdx.y == 0) counts[c] = M;  // 18 writer blocks
    __syncthreads();                               // M is block-uniform -> safe

    float partial = 0.f;
    if (M > 0) {
        const float* __restrict__ row = feature + d * N_PIX;  // F[:,d] contiguous

        // -- stats: mean/var via lane-parallel gather (lst in LDS) --
        float s1 = 0.f, s2 = 0.f;
        for (int j = lane; j < M; j += 64) {
            const float f = row[lst[j]];
            s1 += f;
            s2 += f * f;
        }
#pragma unroll
        for (int o = 32; o; o >>= 1) {
            s1 += __shfl_xor(s1, o);
            s2 += __shfl_xor(s2, o);
        }
        const float cntf = (float)M;
        const float mu = s1 / cntf;
        const float v = fmaxf(s2 / cntf - mu * mu, 1e-12f);

        const float LOG2E = 1.44269504088896340736f;
        const float as = -12.5f * LOG2E / v;   // sample kernel: var/25 -> -0.5*25/v
        const float at = -0.5f * LOG2E / v;    // target
        // lanes >= 51: bin=1e18 -> every exp2 arg is -inf -> contributes 0
        const float bin = (lane < N_B) ? fmaf(0.2f, (float)lane, -5.0f) : 1e18f;
        const float tt = bin - mu;
        const float targ = __builtin_amdgcn_exp2f(at * tt * tt);

        // -- KDE: software-pipelined gather + register broadcast. Tail batch
        //    runs only rem iterations (skipped ones contributed exactly +0.0
        //    before -> bit-identical). Pad f=-1e18 (NOT +1e18: bin sentinel
        //    is +1e18, t would be 0):
        //      lane<51:  t ~ 1e18  -> as*t^2 = -inf -> 0
        //      lane>=51: t ~ 2e18  -> t^2 = inf     -> 0
        float acc_s = 0.f;
        const int Mfull = M & ~63;             // full-batch boundary
        float fl = (lane < M) ? row[lst[lane]] : -1e18f;
        for (int base = 0; base < Mfull; base += 64) {
            const int jn = base + 64 + lane;
            const float fn = (jn < M) ? row[lst[jn]] : -1e18f;  // prefetch b+1
#pragma unroll
            for (int k = 0; k < 64; ++k) {
                const float f = __builtin_amdgcn_readlane(fl, k);  // SGPR broadcast
                const float t = f - bin;       // (f-bin)^2 == (bin-f)^2
                acc_s += __builtin_amdgcn_exp2f(as * t * t);
            }
            fl = fn;
        }
        const int rem = M - Mfull;             // 0..63 tail pixels, fl holds them
#pragma unroll 8
        for (int k = 0; k < rem; ++k) {
            const float f = __builtin_amdgcn_readlane(fl, k);
            const float t = f - bin;
            acc_s += __builtin_amdgcn_exp2f(as * t * t);
        }

        // -- row normalize + smooth-L1 --
        float ss = acc_s, st = targ;
#pragma unroll
        for (int o = 32; o; o >>= 1) {
            ss += __shfl_xor(ss, o);
            st += __shfl_xor(st, o);
        }
        const float hist = acc_s / fmaxf(ss, 1e-30f);
        const float tgt  = targ  / fmaxf(st, 1e-30f);
        const float diff = hist - tgt;
        const float ad = fabsf(diff);
        float sl1 = (ad < 1.f) ? 0.5f * diff * diff : ad - 0.5f;
#pragma unroll
        for (int o = 32; o; o >>= 1) sl1 += __shfl_down(sl1, o);
        partial = sl1;  // valid on lane 0
    }
    if (lane == 0) blk[w] = partial;
    __syncthreads();
    if (threadIdx.x == 0) part[bid] = blk[0] + blk[1] + blk[2] + blk[3];
}

// --- K2: deterministic finalize: single wave sums 1152 partials ---
__global__ __launch_bounds__(64) void k_final(const float* __restrict__ part,
                                              const int* __restrict__ counts,
                                              float* __restrict__ out) {
    const int lane = threadIdx.x;
    float s = 0.f;
    for (int i = lane; i < 18 * 64; i += 64) s += part[i];
#pragma unroll
    for (int o = 32; o; o >>= 1) s += __shfl_xor(s, o);
    if (lane == 0) {
        int active = 0;
        for (int cc = 1; cc < N_C; ++cc) active += (counts[cc] > 0) ? 1 : 0;
        out[0] = s / (float)(N_D * N_B) / ((float)active + 1e-12f);
    }
}

extern "C" void kernel_launch(void* const* d_in, const int* in_sizes, int n_in,
                              void* d_out, int out_size, void* d_ws, size_t ws_size,
                              hipStream_t stream) {
    const float* feature = (const float*)d_in[0];   // [1,256,64,64] fp32
    const int* label = (const int*)d_in[1];         // [1,1,64,64] int32
    float* out = (float*)d_out;                     // [0]=loss, [1..]=feature passthrough
    char* ws = (char*)d_ws;
    float* part = (float*)(ws + OFF_PART);
    int* counts = (int*)(ws + OFF_COUNTS);

    dim3 grid(N_C - 1, N_D / 4);
    k_fused<<<grid, 256, 0, stream>>>(feature, label, out, part, counts);
    k_final<<<1, 64, 0, stream>>>(part, counts, out);
}

// Round 3
// 85.183 us; speedup vs baseline: 1.0851x; 1.0851x over previous
//
#include <hip/hip_runtime.h>

// Problem constants
#define N_PIX 4096   // 64*64 pixels
#define N_D   256    // feature dims
#define N_C   19     // classes
#define N_B   51     // bins

// ws layout (bytes) — every slot written unconditionally each launch (ws is poisoned)
#define OFF_PART   0       // float[18*64] per-block partial losses = 4608 B
#define OFF_COUNTS 4608    // int[19] (counts[1..18] written; [0] never read)

// --- K1 (fully fused): per-block bucket + stats + KDE + smooth-L1 + copy ---
// grid = (18, 64), block 256 = 4 waves; wave = one (c,d) row, lane = bin.
// Each block redundantly compacts class c's pixel list into LDS (labels are
// 16 KB, L2/L3-resident; 1152-way parallel beats a serial 19-block kernel).
// Norm factors 1/sqrt(2*pi*v) are row-constant -> cancel after normalization.
// NOTE (R2 post-mortem): nontemporal passthrough stores and readlane
// broadcasts both REGRESSED (+5.8 us, L2-bypass store backpressure); keep
// plain stores + __shfl. Tail-trim below is bit-identical (removed
// iterations added exactly +0.0).
__global__ __launch_bounds__(256) void k_fused(const float* __restrict__ feature,
                                               const int* __restrict__ label,
                                               float* __restrict__ out,
                                               float* __restrict__ part,
                                               int* __restrict__ counts) {
    const int c = blockIdx.x + 1;                 // class 0 never reaches the loss
    const int w = threadIdx.x >> 6;
    const int lane = threadIdx.x & 63;
    const int d = (blockIdx.y << 2) | w;
    const int bid = blockIdx.x * 64 + blockIdx.y; // 0..1151

    __shared__ int lst[N_PIX];                    // class-c pixel indices (<=16 KB)
    __shared__ int wcnt[4];
    __shared__ float blk[4];

    // -- feature pass-through: striped over all 1152 blocks (4 KB/block),
    //    issued first so the loads/stores overlap everything below --
    {
        const int t = bid * 256 + threadIdx.x;    // 294912 threads total
        for (int i = t; i < N_PIX * N_D; i += 18 * 64 * 256)
            out[1 + i] = feature[i];
    }

    // -- bucket: each wave loads its 1024 labels ONCE into regs, counts,
    //    prefix-sums across waves, then scatters indices into LDS in order --
    int lab[16];
    const int q0 = w << 10;
#pragma unroll
    for (int i = 0; i < 16; ++i) lab[i] = label[q0 + (i << 6) + lane];

    int cnt = 0;
#pragma unroll
    for (int i = 0; i < 16; ++i) cnt += (int)__popcll(__ballot(lab[i] == c));
    if (lane == 0) wcnt[w] = cnt;
    __syncthreads();

    int off = 0, M = 0;
#pragma unroll
    for (int i = 0; i < 4; ++i) { const int v = wcnt[i]; off += (i < w) ? v : 0; M += v; }

#pragma unroll
    for (int i = 0; i < 16; ++i) {
        const bool match = (lab[i] == c);
        const unsigned long long mk = __ballot(match);
        if (match) lst[off + (int)__popcll(mk & ((1ull << lane) - 1ull))] = q0 + (i << 6) + lane;
        off += (int)__popcll(mk);
    }
    if (threadIdx.x == 0 && blockIdx.y == 0) counts[c] = M;  // 18 writer blocks
    __syncthreads();                               // M is block-uniform -> safe

    float partial = 0.f;
    if (M > 0) {
        const float* __restrict__ row = feature + d * N_PIX;  // F[:,d] contiguous

        // -- stats: mean/var via lane-parallel gather (lst now in LDS) --
        float s1 = 0.f, s2 = 0.f;
        for (int j = lane; j < M; j += 64) {
            const float f = row[lst[j]];
            s1 += f;
            s2 += f * f;
        }
#pragma unroll
        for (int o = 32; o; o >>= 1) {
            s1 += __shfl_xor(s1, o);
            s2 += __shfl_xor(s2, o);
        }
        const float cntf = (float)M;
        const float mu = s1 / cntf;
        const float v = fmaxf(s2 / cntf - mu * mu, 1e-12f);

        const float LOG2E = 1.44269504088896340736f;
        const float as = -12.5f * LOG2E / v;   // sample kernel: var/25 -> -0.5*25/v
        const float at = -0.5f * LOG2E / v;    // target
        // lanes >= 51: bin=1e18 -> every exp2 arg is -inf -> contributes 0
        const float bin = (lane < N_B) ? fmaf(0.2f, (float)lane, -5.0f) : 1e18f;
        const float tt = bin - mu;
        const float targ = __builtin_amdgcn_exp2f(at * tt * tt);

        // -- KDE: software-pipelined gather + register broadcast. Full
        //    batches unrolled; tail batch runs only rem iterations (the
        //    skipped ones contributed exactly +0.0 -> bit-identical).
        //    Tail pad f=-1e18 (NOT +1e18: bin sentinel is +1e18, t = 0):
        //      lane<51:  t ~ 1e18  -> as*t^2 = -inf -> 0
        //      lane>=51: t ~ 2e18  -> t^2 = inf     -> 0
        float acc_s = 0.f;
        const int Mfull = M & ~63;             // full-batch boundary
        float fl = (lane < M) ? row[lst[lane]] : -1e18f;
        for (int base = 0; base < Mfull; base += 64) {
            const int jn = base + 64 + lane;
            const float fn = (jn < M) ? row[lst[jn]] : -1e18f;  // prefetch b+1
#pragma unroll
            for (int k = 0; k < 64; ++k) {
                const float f = __shfl(fl, k);
                const float t = f - bin;       // (f-bin)^2 == (bin-f)^2
                acc_s += __builtin_amdgcn_exp2f(as * t * t);
            }
            fl = fn;
        }
        const int rem = M - Mfull;             // 0..63 tail pixels, held in fl
        for (int k = 0; k < rem; ++k) {        // serial chain: no reassociation
            const float f = __shfl(fl, k);
            const float t = f - bin;
            acc_s += __builtin_amdgcn_exp2f(as * t * t);
        }

        // -- row normalize + smooth-L1 --
        float ss = acc_s, st = targ;
#pragma unroll
        for (int o = 32; o; o >>= 1) {
            ss += __shfl_xor(ss, o);
            st += __shfl_xor(st, o);
        }
        const float hist = acc_s / fmaxf(ss, 1e-30f);
        const float tgt  = targ  / fmaxf(st, 1e-30f);
        const float diff = hist - tgt;
        const float ad = fabsf(diff);
        float sl1 = (ad < 1.f) ? 0.5f * diff * diff : ad - 0.5f;
#pragma unroll
        for (int o = 32; o; o >>= 1) sl1 += __shfl_down(sl1, o);
        partial = sl1;  // valid on lane 0
    }
    if (lane == 0) blk[w] = partial;
    __syncthreads();
    if (threadIdx.x == 0) part[bid] = blk[0] + blk[1] + blk[2] + blk[3];
}

// --- K2: deterministic finalize: sum 1152 partials, scale by active classes ---
// (exact R1 structure: 256 threads, same summation order -> absmax 0.0)
__global__ __launch_bounds__(256) void k_final(const float* __restrict__ part,
                                               const int* __restrict__ counts,
                                               float* __restrict__ out) {
    __shared__ float blk[4];
    const int w = threadIdx.x >> 6;
    const int lane = threadIdx.x & 63;
    float s = 0.f;
    for (int i = threadIdx.x; i < 18 * 64; i += 256) s += part[i];
#pragma unroll
    for (int o = 32; o; o >>= 1) s += __shfl_xor(s, o);
    if (lane == 0) blk[w] = s;
    __syncthreads();
    if (threadIdx.x == 0) {
        int active = 0;
        for (int cc = 1; cc < N_C; ++cc) active += (counts[cc] > 0) ? 1 : 0;
        out[0] = (blk[0] + blk[1] + blk[2] + blk[3]) / (float)(N_D * N_B)
                 / ((float)active + 1e-12f);
    }
}

extern "C" void kernel_launch(void* const* d_in, const int* in_sizes, int n_in,
                              void* d_out, int out_size, void* d_ws, size_t ws_size,
                              hipStream_t stream) {
    const float* feature = (const float*)d_in[0];   // [1,256,64,64] fp32
    const int* label = (const int*)d_in[1];         // [1,1,64,64] int32
    float* out = (float*)d_out;                     // [0]=loss, [1..]=feature passthrough
    char* ws = (char*)d_ws;
    float* part = (float*)(ws + OFF_PART);
    int* counts = (int*)(ws + OFF_COUNTS);

    dim3 grid(N_C - 1, N_D / 4);
    k_fused<<<grid, 256, 0, stream>>>(feature, label, out, part, counts);
    k_final<<<1, 256, 0, stream>>>(part, counts, out);
}